// Round 2
// baseline (69.490 us; speedup 1.0000x reference)
//
#include <hip/hip_runtime.h>

// Problem constants (from reference init_kwargs)
#define BB   64
#define KP   21
#define HH   256
#define KS   9
#define PADK 4   // KS/2

#define NPLANES          (BB * KP)          // 1344
#define F4_PER_PLANE     (HH * HH / 4)      // 16384 float4 per plane
#define BLOCKS_PER_PLANE 4
#define THREADS          256
#define F4_PER_THREAD    (F4_PER_PLANE / (BLOCKS_PER_PLANE * THREADS)) // 16

// Fused zero + Gaussian-patch scatter. Each (b,k) plane has exactly one
// spike at (r,c); output = 10*kernel2d in the clipped 9x9 patch, 0 elsewhere.
// Every output element is written exactly once per call (deterministic, no
// reliance on buffer state).
__global__ __launch_bounds__(THREADS)
void heatmap_fused_kernel(const int* __restrict__ x,
                          const float* __restrict__ k2d,
                          float4* __restrict__ out) {
    const int p   = blockIdx.x / BLOCKS_PER_PLANE;   // plane 0..1343
    const int sub = blockIdx.x % BLOCKS_PER_PLANE;
    const int t   = threadIdx.x;

    const int r = x[2 * p];
    const int c = x[2 * p + 1];

    float4* plane = out + (size_t)p * F4_PER_PLANE;
    const float4 z = make_float4(0.f, 0.f, 0.f, 0.f);

#pragma unroll
    for (int ch = 0; ch < F4_PER_THREAD; ++ch) {
        // consecutive threads -> consecutive float4s (1 KiB / wave / store)
        const int f4   = sub * (F4_PER_PLANE / BLOCKS_PER_PLANE) + ch * THREADS + t;
        const int i    = f4 >> 6;          // row 0..255
        const int col0 = (f4 & 63) << 2;   // first col of this float4

        float4 v = z;
        if (i >= r - PADK && i <= r + PADK &&
            col0 + 3 >= c - PADK && col0 <= c + PADK) {
            const int di = r - i + PADK;   // 0..8 guaranteed by row check
            float vals[4];
#pragma unroll
            for (int e = 0; e < 4; ++e) {
                const int dj = c - (col0 + e) + PADK;
                vals[e] = (dj >= 0 && dj < KS) ? 10.0f * k2d[di * KS + dj] : 0.0f;
            }
            v = make_float4(vals[0], vals[1], vals[2], vals[3]);
        }
        plane[f4] = v;
    }
}

extern "C" void kernel_launch(void* const* d_in, const int* in_sizes, int n_in,
                              void* d_out, int out_size, void* d_ws, size_t ws_size,
                              hipStream_t stream) {
    const int*   x   = (const int*)d_in[0];    // [B, KP, 2] int32
    const float* k2d = (const float*)d_in[1];  // [KS, KS] float32
    float4*      out = (float4*)d_out;         // [B, KP, H, H] float32

    heatmap_fused_kernel<<<NPLANES * BLOCKS_PER_PLANE, THREADS, 0, stream>>>(x, k2d, out);
}